// Round 3
// baseline (21632.767 us; speedup 1.0000x reference)
//
#include <hip/hip_runtime.h>
#include <stdint.h>

// B=64, T=512, D=512, U=1024, 4U=4096
// Workspace (total ~34 MB):
//   xb  : [T*64][512] bf16 = 33,554,432   (x transposed to [t][b][d], bf16)
//   h   : [2][64][1024] bf16 = 262,144    (double buffer)
//   cnt : 4 group counters, 1 KB apart = 4,096
#define WS_XB   0LL
#define WS_H    33554432LL
#define WS_CNT  33816576LL

typedef unsigned short u16;
typedef __attribute__((ext_vector_type(8))) short short8;
typedef __attribute__((ext_vector_type(4))) float f32x4;

__device__ __forceinline__ u16 f2bf(float f) {
  unsigned u = __float_as_uint(f);
  u += 0x7FFFu + ((u >> 16) & 1u);   // round-to-nearest-even
  return (u16)(u >> 16);
}

// ---------- conv: x [64][512][512] f32 -> xb [(t*64+b)][512] bf16 ----------
__global__ void conv_x(const float* __restrict__ x, u16* __restrict__ xb) {
  long gid = (long)blockIdx.x * blockDim.x + threadIdx.x;  // 2,097,152 threads
  long sr = gid >> 6;            // source row = b*512 + t
  int  d0 = (int)(gid & 63) * 8;
  int  b = (int)(sr >> 9), t = (int)(sr & 511);
  const float* src = x + sr * 512 + d0;
  float4 v0 = *(const float4*)(src);
  float4 v1 = *(const float4*)(src + 4);
  u16 tmp[8] = {f2bf(v0.x), f2bf(v0.y), f2bf(v0.z), f2bf(v0.w),
                f2bf(v1.x), f2bf(v1.y), f2bf(v1.z), f2bf(v1.w)};
  *(short8*)(xb + ((long)t * 64 + b) * 512 + d0) = *(short8*)tmp;
}

// ---------- fused LSTM: 256 WGs = 4 batch-groups x 64 u-tiles, persistent ----------
// Plain launch (NOT cooperative — that API failed on this stack). Safe because:
// 256 WGs, 1 WG/CU resources (54KB LDS, <=256 VGPR) on 256 CUs -> all resident;
// barrier only needs the 64 WGs of one batch-group, via monotonic device-scope
// atomic counter (no dispatch-order assumption; counters are cumulative).
// WG (bg,ut): batches bg*16..+16, u's ut*16..+16, wave w = gate w (i,f,g,o).
// Weights: 48 register B-fragments/wave (wf[0..31]=rec_kernel K=1024, wf[32..47]=kernel K=512).
// LDS: A-tile [16 rows][1544] bf16 (cols 0..1023 = h, 1024..1535 = x_t, 8 pad) + zbuf.
#define SMA_LD 1544

__launch_bounds__(256, 1)
__global__ void lstm_fused(const float* __restrict__ kern, const float* __restrict__ rec,
                           const u16* __restrict__ xb, u16* __restrict__ hbuf,
                           unsigned int* __restrict__ cnt, float* __restrict__ out) {
  __shared__ u16  smA[16 * SMA_LD];      // 49,408 B
  __shared__ float zbuf[4 * 16 * 17];    //  4,352 B

  const int bid = blockIdx.x;
  const int bg = bid >> 6;   // 0..3 batch group (64 WGs each)
  const int ut = bid & 63;   // 0..63 u tile
  const int tid = threadIdx.x;
  const int w = tid >> 6, lane = tid & 63;
  const int quad = lane >> 4, n15 = lane & 15;

  // ---- one-time: load 48 B-fragments into registers ----
  // B-frag for 16x16x32: n = lane&15, k = quad*8 + j. Our col = w*1024 + ut*16 + n15.
  short8 wf[48];
  const size_t gcol = (size_t)w * 1024 + (size_t)ut * 16 + (size_t)n15;
#pragma unroll
  for (int ks = 0; ks < 32; ++ks) {
    u16 tmp[8];
#pragma unroll
    for (int j = 0; j < 8; ++j)
      tmp[j] = f2bf(rec[(size_t)(ks * 32 + quad * 8 + j) * 4096 + gcol]);
    wf[ks] = *(short8*)tmp;
  }
#pragma unroll
  for (int ks = 0; ks < 16; ++ks) {
    u16 tmp[8];
#pragma unroll
    for (int j = 0; j < 8; ++j)
      tmp[j] = f2bf(kern[(size_t)(ks * 32 + quad * 8 + j) * 4096 + gcol]);
    wf[32 + ks] = *(short8*)tmp;
  }

  const int bl = tid >> 4;   // elementwise: batch-local 0..15
  const int ul = tid & 15;   // elementwise: u-local 0..15
  float c = 0.f;

  const u16* arow_p = smA + n15 * SMA_LD + quad * 8;  // A-frag base (m=n15)

  for (int t = 0; t < 512; ++t) {
    const int pr = t & 1;

    // ---- stage [h | x_t] tile into LDS (padded rows -> bank-friendly b128) ----
    const u16* hsrc = hbuf + (size_t)pr * 65536 + (size_t)bg * 16 * 1024;
#pragma unroll
    for (int j = 0; j < 8; ++j) {           // 16 rows x 2048 B of h
      int idx = tid + j * 256;              // 16B-chunk id 0..2047
      int r = idx >> 7, c16 = idx & 127;
      uint4 v = *(const uint4*)(hsrc + (size_t)r * 1024 + c16 * 8);
      *(uint4*)(smA + r * SMA_LD + c16 * 8) = v;
    }
    const u16* xsrc = xb + ((size_t)t * 64 + bg * 16) * 512;
#pragma unroll
    for (int j = 0; j < 4; ++j) {           // 16 rows x 1024 B of x_t
      int idx = tid + j * 256;              // 0..1023
      int r = idx >> 6, c16 = idx & 63;
      uint4 v = *(const uint4*)(xsrc + (size_t)r * 512 + c16 * 8);
      *(uint4*)(smA + r * SMA_LD + 1024 + c16 * 8) = v;
    }
    __syncthreads();

    // ---- z = [h|x] @ [R;K] for this wave's gate, 16 u cols, 16 batches ----
    f32x4 acc0 = {0.f, 0.f, 0.f, 0.f}, acc1 = {0.f, 0.f, 0.f, 0.f};
#pragma unroll
    for (int ks = 0; ks < 48; ks += 2) {
      short8 a0 = *(const short8*)(arow_p + ks * 32);
      acc0 = __builtin_amdgcn_mfma_f32_16x16x32_bf16(a0, wf[ks], acc0, 0, 0, 0);
      short8 a1 = *(const short8*)(arow_p + ks * 32 + 32);
      acc1 = __builtin_amdgcn_mfma_f32_16x16x32_bf16(a1, wf[ks + 1], acc1, 0, 0, 0);
    }

    // ---- z exchange: zbuf[gate=w][batch=quad*4+r][u=n15] ----
    float* zp = zbuf + (w * 16 + quad * 4) * 17 + n15;
    zp[0]  = acc0[0] + acc1[0];
    zp[17] = acc0[1] + acc1[1];
    zp[34] = acc0[2] + acc1[2];
    zp[51] = acc0[3] + acc1[3];
    __syncthreads();

    float zi = zbuf[(0 * 16 + bl) * 17 + ul];
    float zf = zbuf[(1 * 16 + bl) * 17 + ul];
    float zg = zbuf[(2 * 16 + bl) * 17 + ul];
    float zo = zbuf[(3 * 16 + bl) * 17 + ul];
    float ig = 1.f / (1.f + __expf(-zi));
    float fg = 1.f / (1.f + __expf(-zf));
    float gg = tanhf(zg);
    float og = 1.f / (1.f + __expf(-zo));
    c = fg * c + ig * gg;
    float h = og * tanhf(c);

    const size_t hidx = (size_t)(bg * 16 + bl) * 1024 + (size_t)ut * 16 + ul;
    hbuf[(size_t)(pr ^ 1) * 65536 + hidx] = f2bf(h);

    if (t == 511) {
      out[hidx] = h;
    } else {
      __threadfence();       // release: make h writes agent-visible
      __syncthreads();
      if (tid == 0) {
        __hip_atomic_fetch_add(&cnt[bg * 256], 1u, __ATOMIC_RELEASE, __HIP_MEMORY_SCOPE_AGENT);
        const unsigned target = 64u * (unsigned)(t + 1);
        while (__hip_atomic_load(&cnt[bg * 256], __ATOMIC_ACQUIRE, __HIP_MEMORY_SCOPE_AGENT) < target)
          __builtin_amdgcn_s_sleep(2);
      }
      __syncthreads();
      __threadfence();       // acquire: invalidate before reading peers' h
    }
  }
}

extern "C" void kernel_launch(void* const* d_in, const int* in_sizes, int n_in,
                              void* d_out, int out_size, void* d_ws, size_t ws_size,
                              hipStream_t stream) {
  const float* x    = (const float*)d_in[0];
  const float* kern = (const float*)d_in[1];
  const float* rec  = (const float*)d_in[2];
  float* out = (float*)d_out;
  char* ws = (char*)d_ws;

  u16*      xbp  = (u16*)(ws + WS_XB);
  u16*      hbuf = (u16*)(ws + WS_H);
  unsigned* cnt  = (unsigned*)(ws + WS_CNT);

  // zero h double-buffer + barrier counters (ws is re-poisoned before every launch)
  hipMemsetAsync(ws + WS_H, 0, 262144 + 4096, stream);

  conv_x<<<8192, 256, 0, stream>>>(x, xbp);

  lstm_fused<<<256, 256, 0, stream>>>(kern, rec, xbp, hbuf, cnt, out);
}

// Round 4
// 7073.923 us; speedup vs baseline: 3.0581x; 3.0581x over previous
//
#include <hip/hip_runtime.h>
#include <stdint.h>

// B=64, T=512, D=512, U=1024, 4U=4096
// Workspace:
//   xb    : [T*64][512] bf16 = 33,554,432  (x as [t][b][d], bf16)
//   hbuf  : [2][64][512] u32 (bf16 pairs) = 262,144
//   flags : u32[4][64] = 1,024  (per-WG barrier flags, monotonic)
#define WS_XB   0LL
#define WS_H    33554432LL
#define WS_FLAG 33816576LL

typedef unsigned short u16;
typedef unsigned int   u32;
typedef __attribute__((ext_vector_type(8))) short short8;
typedef __attribute__((ext_vector_type(4))) float f32x4;

__device__ __forceinline__ u16 f2bf(float f) {
  unsigned u = __float_as_uint(f);
  u += 0x7FFFu + ((u >> 16) & 1u);   // round-to-nearest-even
  return (u16)(u >> 16);
}

// ---------- conv: x [64][512][512] f32 -> xb [(t*64+b)][512] bf16 ----------
__global__ void conv_x(const float* __restrict__ x, u16* __restrict__ xb) {
  long gid = (long)blockIdx.x * blockDim.x + threadIdx.x;  // 2,097,152 threads
  long sr = gid >> 6;            // source row = b*512 + t
  int  d0 = (int)(gid & 63) * 8;
  int  b = (int)(sr >> 9), t = (int)(sr & 511);
  const float* src = x + sr * 512 + d0;
  float4 v0 = *(const float4*)(src);
  float4 v1 = *(const float4*)(src + 4);
  u16 tmp[8] = {f2bf(v0.x), f2bf(v0.y), f2bf(v0.z), f2bf(v0.w),
                f2bf(v1.x), f2bf(v1.y), f2bf(v1.z), f2bf(v1.w)};
  *(short8*)(xb + ((long)t * 64 + b) * 512 + d0) = *(short8*)tmp;
}

// ---------- fused LSTM: 256 WGs = 4 batch-groups x 64 u-tiles, persistent ----------
// Barrier (per 64-WG batch-group), fence-free:
//   writer: h as relaxed agent-scope u32 stores (cache-bypass -> LLC), then ONE
//           release store to its own flag (flags are per-WG: no RMW, no line ping-pong)
//   reader: wave0 polls 64 flags with relaxed agent loads (LLC, no invalidates),
//           then all threads load h with relaxed agent u32 loads (LLC).
// No __threadfence anywhere -> L2 stays warm for x tiles.
#define SMA_LD 1544   // u16/row: 1024 h | 512 x | 8 pad

__launch_bounds__(256, 1)
__global__ void lstm_fused(const float* __restrict__ kern, const float* __restrict__ rec,
                           const u16* __restrict__ xb, u32* __restrict__ hbuf,
                           u32* __restrict__ flags, float* __restrict__ out) {
  __shared__ u16   smA[16 * SMA_LD];     // 49,408 B
  __shared__ float zbuf[4 * 16 * 17];    //  4,352 B
  __shared__ u16   hstage[256];          //    512 B

  const int bid = blockIdx.x;
  const int bg = bid >> 6;   // 0..3 batch group (64 WGs each)
  const int ut = bid & 63;   // 0..63 u tile
  const int tid = threadIdx.x;
  const int w = tid >> 6, lane = tid & 63;
  const int quad = lane >> 4, n15 = lane & 15;

  // ---- one-time: 48 register B-fragments (wf[0..31]=rec K=1024, wf[32..47]=kern K=512)
  short8 wf[48];
  const size_t gcol = (size_t)w * 1024 + (size_t)ut * 16 + (size_t)n15;
#pragma unroll
  for (int ks = 0; ks < 32; ++ks) {
    u16 tmp[8];
#pragma unroll
    for (int j = 0; j < 8; ++j)
      tmp[j] = f2bf(rec[(size_t)(ks * 32 + quad * 8 + j) * 4096 + gcol]);
    wf[ks] = *(short8*)tmp;
  }
#pragma unroll
  for (int ks = 0; ks < 16; ++ks) {
    u16 tmp[8];
#pragma unroll
    for (int j = 0; j < 8; ++j)
      tmp[j] = f2bf(kern[(size_t)(ks * 32 + quad * 8 + j) * 4096 + gcol]);
    wf[32 + ks] = *(short8*)tmp;
  }

  const int bl = tid >> 4;   // elementwise: batch-local 0..15
  const int ul = tid & 15;   // elementwise: u-local 0..15
  float c = 0.f;

  const u16* arow_p = smA + n15 * SMA_LD + quad * 8;  // A-frag base (m=n15)

  // ---- prologue: h0 = 0 in LDS; stage x0 ----
#pragma unroll
  for (int j = 0; j < 8; ++j) {
    int idx = tid + j * 256;           // 0..2047, 8B chunks of h region
    int r = idx >> 7, c8 = idx & 127;
    *(uint4*)(smA + r * SMA_LD + c8 * 8) = (uint4){0u, 0u, 0u, 0u};
  }
  {
    const u16* xsrc = xb + (size_t)(bg * 16) * 512;
#pragma unroll
    for (int j = 0; j < 4; ++j) {
      int idx = tid + j * 256;
      int r = idx >> 6, c16 = idx & 63;
      uint4 v = *(const uint4*)(xsrc + (size_t)r * 512 + c16 * 8);
      *(uint4*)(smA + r * SMA_LD + 1024 + c16 * 8) = v;
    }
  }
  __syncthreads();

  for (int t = 0; t < 512; ++t) {
    // ---- z = [h|x] @ [R;K] for this wave's gate (16 u cols x 16 batches) ----
    f32x4 acc0 = {0.f, 0.f, 0.f, 0.f}, acc1 = {0.f, 0.f, 0.f, 0.f};
#pragma unroll
    for (int ks = 0; ks < 48; ks += 2) {
      short8 a0 = *(const short8*)(arow_p + ks * 32);
      acc0 = __builtin_amdgcn_mfma_f32_16x16x32_bf16(a0, wf[ks], acc0, 0, 0, 0);
      short8 a1 = *(const short8*)(arow_p + ks * 32 + 32);
      acc1 = __builtin_amdgcn_mfma_f32_16x16x32_bf16(a1, wf[ks + 1], acc1, 0, 0, 0);
    }

    // ---- z exchange: zbuf[gate=w][batch=quad*4+r][u=n15] ----
    float* zp = zbuf + (w * 16 + quad * 4) * 17 + n15;
    zp[0]  = acc0[0] + acc1[0];
    zp[17] = acc0[1] + acc1[1];
    zp[34] = acc0[2] + acc1[2];
    zp[51] = acc0[3] + acc1[3];
    __syncthreads();                       // sync1: z ready; all MFMA reads done

    float zi = zbuf[(0 * 16 + bl) * 17 + ul];
    float zf = zbuf[(1 * 16 + bl) * 17 + ul];
    float zg = zbuf[(2 * 16 + bl) * 17 + ul];
    float zo = zbuf[(3 * 16 + bl) * 17 + ul];
    float ig = 1.f / (1.f + __expf(-zi));
    float fg = 1.f / (1.f + __expf(-zf));
    float gg = tanhf(zg);
    float og = 1.f / (1.f + __expf(-zo));
    c = fg * c + ig * gg;
    float h = og * tanhf(c);

    if (t == 511) {
      out[(size_t)(bg * 16 + bl) * 1024 + (size_t)ut * 16 + ul] = h;
      break;
    }

    hstage[bl * 16 + ul] = f2bf(h);
    __syncthreads();                       // sync2: hstage ready; smA safe to restage

    const int pb = (t + 1) & 1;            // buffer receiving h_{t+1}
    // ---- publish h patch: 128 threads, u32 (bf16 pair), cache-bypass to LLC ----
    if (tid < 128) {
      u32 v = *(const u32*)&hstage[2 * tid];
      int r = tid >> 3, c2 = tid & 7;      // 16 rows x 8 u32
      __hip_atomic_store(&hbuf[(size_t)pb * 32768 + (size_t)(bg * 16 + r) * 512 + ut * 8 + c2],
                         v, __ATOMIC_RELAXED, __HIP_MEMORY_SCOPE_AGENT);
    }

    // ---- overlap: stage x_{t+1} while the flag/poll round-trip is in flight ----
    {
      const u16* xsrc = xb + ((size_t)(t + 1) * 64 + bg * 16) * 512;
#pragma unroll
      for (int j = 0; j < 4; ++j) {
        int idx = tid + j * 256;
        int r = idx >> 6, c16 = idx & 63;
        uint4 v = *(const uint4*)(xsrc + (size_t)r * 512 + c16 * 8);
        *(uint4*)(smA + r * SMA_LD + 1024 + c16 * 8) = v;
      }
    }

    // ---- signal: one RELEASE store to OWN flag (orders the h stores above) ----
    if (tid == 0)
      __hip_atomic_store(&flags[bg * 64 + ut], (u32)(t + 1),
                         __ATOMIC_RELEASE, __HIP_MEMORY_SCOPE_AGENT);

    // ---- wait: wave0 polls all 64 flags of its group (relaxed, LLC, no inval) ----
    if (w == 0) {
      const u32 tgt = (u32)(t + 1);
      const u32* fp = &flags[bg * 64 + lane];
      u32 v = __hip_atomic_load(fp, __ATOMIC_RELAXED, __HIP_MEMORY_SCOPE_AGENT);
      while (__ballot(v < tgt) != 0ull) {
        __builtin_amdgcn_s_sleep(1);
        v = __hip_atomic_load(fp, __ATOMIC_RELAXED, __HIP_MEMORY_SCOPE_AGENT);
      }
    }
    __syncthreads();                       // sync3: barrier passed for all waves
    asm volatile("" ::: "memory");

    // ---- stage h_{t+1}: 32KB via relaxed agent u32 loads (LLC) -> LDS ----
    {
      const u32* hs = hbuf + (size_t)pb * 32768 + (size_t)bg * 16 * 512;
#pragma unroll
      for (int j = 0; j < 32; ++j) {
        int idx = tid + j * 256;           // 0..8191
        int r = idx >> 9, c2 = idx & 511;
        u32 v = __hip_atomic_load(&hs[(size_t)r * 512 + c2],
                                  __ATOMIC_RELAXED, __HIP_MEMORY_SCOPE_AGENT);
        *(u32*)&smA[r * SMA_LD + c2 * 2] = v;
      }
    }
    __syncthreads();                       // sync4: smA ready for next MFMA
  }
}

extern "C" void kernel_launch(void* const* d_in, const int* in_sizes, int n_in,
                              void* d_out, int out_size, void* d_ws, size_t ws_size,
                              hipStream_t stream) {
  const float* x    = (const float*)d_in[0];
  const float* kern = (const float*)d_in[1];
  const float* rec  = (const float*)d_in[2];
  float* out = (float*)d_out;
  char* ws = (char*)d_ws;

  u16* xbp   = (u16*)(ws + WS_XB);
  u32* hbuf  = (u32*)(ws + WS_H);
  u32* flags = (u32*)(ws + WS_FLAG);

  // zero barrier flags (ws is re-poisoned to 0xAA before every launch)
  hipMemsetAsync(ws + WS_FLAG, 0, 1024, stream);

  conv_x<<<8192, 256, 0, stream>>>(x, xbp);

  lstm_fused<<<256, 256, 0, stream>>>(kern, rec, xbp, hbuf, flags, out);
}

// Round 5
// 4828.865 us; speedup vs baseline: 4.4799x; 1.4649x over previous
//
#include <hip/hip_runtime.h>
#include <stdint.h>

// B=64, T=512, D=512, U=1024, 4U=4096
// Workspace:
//   xb    : [T*64][512] bf16 = 33,554,432  (x as [t][b][d], bf16)
//   hbuf  : [2][64][512] u32 (bf16 pairs) = 262,144
//   flags : u32[4][64] = 1,024  (per-WG barrier flags, monotonic)
#define WS_XB   0LL
#define WS_H    33554432LL
#define WS_FLAG 33816576LL

typedef unsigned short u16;
typedef unsigned int   u32;
typedef unsigned long long u64;
typedef __attribute__((ext_vector_type(8))) short short8;
typedef __attribute__((ext_vector_type(4))) float f32x4;

__device__ __forceinline__ u16 f2bf(float f) {
  unsigned u = __float_as_uint(f);
  u += 0x7FFFu + ((u >> 16) & 1u);   // round-to-nearest-even
  return (u16)(u >> 16);
}

// ---------- conv: x [64][512][512] f32 -> xb [(t*64+b)][512] bf16 ----------
__global__ void conv_x(const float* __restrict__ x, u16* __restrict__ xb) {
  long gid = (long)blockIdx.x * blockDim.x + threadIdx.x;  // 2,097,152 threads
  long sr = gid >> 6;            // source row = b*512 + t
  int  d0 = (int)(gid & 63) * 8;
  int  b = (int)(sr >> 9), t = (int)(sr & 511);
  const float* src = x + sr * 512 + d0;
  float4 v0 = *(const float4*)(src);
  float4 v1 = *(const float4*)(src + 4);
  u16 tmp[8] = {f2bf(v0.x), f2bf(v0.y), f2bf(v0.z), f2bf(v0.w),
                f2bf(v1.x), f2bf(v1.y), f2bf(v1.z), f2bf(v1.w)};
  *(short8*)(xb + ((long)t * 64 + b) * 512 + d0) = *(short8*)tmp;
}

// ---------- fused LSTM: 256 WGs = 4 batch-groups x 64 u-tiles, persistent ----------
// LDS h tile is FRAG-ORDERED: smH[ks][lane][8] u16 -> ds_read_b128 at
// (ks*64+lane)*16 bytes is lane-contiguous = conflict-free, identical for all
// 4 waves. x_t A-frags live in registers (prefetched post-release, cached loads).
// Barrier: per-WG flag (release store) + wave0 poll of 64 flags (relaxed, LLC).
__launch_bounds__(256, 1)
__global__ void lstm_fused(const float* __restrict__ kern, const float* __restrict__ rec,
                           const u16* __restrict__ xb, u32* __restrict__ hbuf,
                           u32* __restrict__ flags, float* __restrict__ out) {
  __shared__ u16   smH[32 * 64 * 8];     // 32,768 B, frag-ordered
  __shared__ float zbuf[4 * 16 * 17];    //  4,352 B

  const int bid = blockIdx.x;
  const int bg = bid >> 6;   // 0..3 batch group (64 WGs each)
  const int ut = bid & 63;   // 0..63 u tile
  const int tid = threadIdx.x;
  const int w = tid >> 6, lane = tid & 63;
  const int quad = lane >> 4, n15 = lane & 15;

  // ---- one-time: 48 register B-fragments (wf[0..31]=rec K=1024, wf[32..47]=kern K=512)
  short8 wf[48];
  const size_t gcol = (size_t)w * 1024 + (size_t)ut * 16 + (size_t)n15;
#pragma unroll
  for (int ks = 0; ks < 32; ++ks) {
    u16 tmp[8];
#pragma unroll
    for (int j = 0; j < 8; ++j)
      tmp[j] = f2bf(rec[(size_t)(ks * 32 + quad * 8 + j) * 4096 + gcol]);
    wf[ks] = *(short8*)tmp;
  }
#pragma unroll
  for (int ks = 0; ks < 16; ++ks) {
    u16 tmp[8];
#pragma unroll
    for (int j = 0; j < 8; ++j)
      tmp[j] = f2bf(kern[(size_t)(ks * 32 + quad * 8 + j) * 4096 + gcol]);
    wf[32 + ks] = *(short8*)tmp;
  }

  const int bl = tid >> 4;   // elementwise: batch-local 0..15
  const int ul = tid & 15;   // elementwise: u-local 0..15
  float c = 0.f;

  // ---- prologue: h0 = 0 in LDS; x0 A-frags -> registers ----
#pragma unroll
  for (int j = 0; j < 8; ++j)
    *(uint4*)(smH + (tid + j * 256) * 8) = (uint4){0u, 0u, 0u, 0u};

  short8 xf[16];
  {
    const u16* xr = xb + (size_t)(bg * 16 + n15) * 512 + quad * 8;
#pragma unroll
    for (int ks = 0; ks < 16; ++ks) xf[ks] = *(const short8*)(xr + ks * 32);
  }
  __syncthreads();

  for (int t = 0; t < 512; ++t) {
    // ---- z = h@R (LDS frags) + x@K (reg frags), dual acc chains ----
    f32x4 acc0 = {0.f, 0.f, 0.f, 0.f}, acc1 = {0.f, 0.f, 0.f, 0.f};
#pragma unroll
    for (int ks = 0; ks < 32; ks += 2) {
      short8 a0 = *(const short8*)(smH + (ks * 64 + lane) * 8);
      acc0 = __builtin_amdgcn_mfma_f32_16x16x32_bf16(a0, wf[ks], acc0, 0, 0, 0);
      short8 a1 = *(const short8*)(smH + ((ks + 1) * 64 + lane) * 8);
      acc1 = __builtin_amdgcn_mfma_f32_16x16x32_bf16(a1, wf[ks + 1], acc1, 0, 0, 0);
    }
#pragma unroll
    for (int ks = 0; ks < 16; ks += 2) {
      acc0 = __builtin_amdgcn_mfma_f32_16x16x32_bf16(xf[ks], wf[32 + ks], acc0, 0, 0, 0);
      acc1 = __builtin_amdgcn_mfma_f32_16x16x32_bf16(xf[ks + 1], wf[33 + ks], acc1, 0, 0, 0);
    }

    // ---- z exchange: zbuf[gate=w][batch=quad*4+r][u=n15] ----
    float* zp = zbuf + (w * 16 + quad * 4) * 17 + n15;
    zp[0]  = acc0[0] + acc1[0];
    zp[17] = acc0[1] + acc1[1];
    zp[34] = acc0[2] + acc1[2];
    zp[51] = acc0[3] + acc1[3];
    __syncthreads();                       // sync1: z ready; MFMA LDS reads done

    float zi = zbuf[(0 * 16 + bl) * 17 + ul];
    float zf = zbuf[(1 * 16 + bl) * 17 + ul];
    float zg = zbuf[(2 * 16 + bl) * 17 + ul];
    float zo = zbuf[(3 * 16 + bl) * 17 + ul];
    float ig = 1.f / (1.f + __expf(-zi));
    float fg = 1.f / (1.f + __expf(-zf));
    float gg = tanhf(zg);
    float og = 1.f / (1.f + __expf(-zo));
    c = fg * c + ig * gg;
    float h = og * tanhf(c);

    if (t == 511) {
      out[(size_t)(bg * 16 + bl) * 1024 + (size_t)ut * 16 + ul] = h;
      break;
    }

    const int pb = (t + 1) & 1;            // buffer receiving h_{t+1}

    // ---- publish straight from registers: pair-pack via shfl, even lanes store ----
    {
      u16 hu = f2bf(h);
      int other = __shfl_xor((int)(unsigned)hu, 1);
      if ((tid & 1) == 0) {
        u32 v = (u32)hu | ((u32)(unsigned)other << 16);
        __hip_atomic_store(&hbuf[(size_t)pb * 32768 + (size_t)(bg * 16 + bl) * 512
                                 + ut * 8 + (ul >> 1)],
                           v, __ATOMIC_RELAXED, __HIP_MEMORY_SCOPE_AGENT);
      }
    }

    // ---- signal: one RELEASE store to OWN flag (waits only on the publish) ----
    if (tid == 0)
      __hip_atomic_store(&flags[bg * 64 + ut], (u32)(t + 1),
                         __ATOMIC_RELEASE, __HIP_MEMORY_SCOPE_AGENT);

    // ---- x_{t+2... actually t+1} A-frag prefetch (cached, off critical path) ----
    {
      const u16* xr = xb + ((size_t)(t + 1) * 64 + bg * 16 + n15) * 512 + quad * 8;
#pragma unroll
      for (int ks = 0; ks < 16; ++ks) xf[ks] = *(const short8*)(xr + ks * 32);
    }

    // ---- wait: wave0 polls its group's 64 flags (relaxed, LLC, no inval) ----
    if (w == 0) {
      const u32 tgt = (u32)(t + 1);
      const u32* fp = &flags[bg * 64 + lane];
      u32 v = __hip_atomic_load(fp, __ATOMIC_RELAXED, __HIP_MEMORY_SCOPE_AGENT);
      while (__ballot(v < tgt) != 0ull) {
        __builtin_amdgcn_s_sleep(1);
        v = __hip_atomic_load(fp, __ATOMIC_RELAXED, __HIP_MEMORY_SCOPE_AGENT);
      }
    }
    __syncthreads();                       // sync3: barrier passed for all waves

    // ---- reload h_{t+1} -> smH (frag order). thread: ks = w*8+kk, lane slot ----
    {
      const u32* hs = hbuf + (size_t)pb * 32768 + (size_t)(bg * 16 + n15) * 512;
#pragma unroll
      for (int kk = 0; kk < 8; ++kk) {
        const int ks = w * 8 + kk;
        const u64* src = (const u64*)(hs + ks * 16 + quad * 4);
        u64 v0 = __hip_atomic_load(src,     __ATOMIC_RELAXED, __HIP_MEMORY_SCOPE_AGENT);
        u64 v1 = __hip_atomic_load(src + 1, __ATOMIC_RELAXED, __HIP_MEMORY_SCOPE_AGENT);
        u64 pair[2] = {v0, v1};
        *(uint4*)(smH + (ks * 64 + lane) * 8) = *(const uint4*)pair;
      }
    }
    __syncthreads();                       // sync4: smH ready for next MFMA
  }
}

extern "C" void kernel_launch(void* const* d_in, const int* in_sizes, int n_in,
                              void* d_out, int out_size, void* d_ws, size_t ws_size,
                              hipStream_t stream) {
  const float* x    = (const float*)d_in[0];
  const float* kern = (const float*)d_in[1];
  const float* rec  = (const float*)d_in[2];
  float* out = (float*)d_out;
  char* ws = (char*)d_ws;

  u16* xbp   = (u16*)(ws + WS_XB);
  u32* hbuf  = (u32*)(ws + WS_H);
  u32* flags = (u32*)(ws + WS_FLAG);

  // zero barrier flags (ws is re-poisoned to 0xAA before every launch)
  hipMemsetAsync(ws + WS_FLAG, 0, 1024, stream);

  conv_x<<<8192, 256, 0, stream>>>(x, xbp);

  lstm_fused<<<256, 256, 0, stream>>>(kern, rec, xbp, hbuf, flags, out);
}

// Round 6
// 3444.362 us; speedup vs baseline: 6.2806x; 1.4020x over previous
//
#include <hip/hip_runtime.h>
#include <stdint.h>

// B=64, T=512, D=512, U=1024, 4U=4096
// Workspace:
//   xb    : [T*64][512] bf16 = 33,554,432  (x as [t][b][d], bf16)
//   hbuf  : [2][64][512] u32 (bf16 pairs) = 262,144
//   flags : u32[256][32] = 32,768  (one 128-B line per WG flag, monotonic)
#define WS_XB   0LL
#define WS_H    33554432LL
#define WS_FLAG 33816576LL

typedef unsigned short u16;
typedef unsigned int   u32;
typedef unsigned long long u64;
typedef __attribute__((ext_vector_type(8))) short short8;
typedef __attribute__((ext_vector_type(4))) float f32x4;

__device__ __forceinline__ u16 f2bf(float f) {
  unsigned u = __float_as_uint(f);
  u += 0x7FFFu + ((u >> 16) & 1u);   // round-to-nearest-even
  return (u16)(u >> 16);
}
__device__ __forceinline__ float fast_tanh(float x) {
  // tanh(x) = 1 - 2/(e^{2x}+1); exact limits at +-inf, monotone, ~1ulp-ish
  float e = __expf(2.f * x);
  return 1.f - 2.f / (e + 1.f);
}

// ---------- conv: x [64][512][512] f32 -> xb [(t*64+b)][512] bf16 ----------
__global__ void conv_x(const float* __restrict__ x, u16* __restrict__ xb) {
  long gid = (long)blockIdx.x * blockDim.x + threadIdx.x;  // 2,097,152 threads
  long sr = gid >> 6;            // source row = b*512 + t
  int  d0 = (int)(gid & 63) * 8;
  int  b = (int)(sr >> 9), t = (int)(sr & 511);
  const float* src = x + sr * 512 + d0;
  float4 v0 = *(const float4*)(src);
  float4 v1 = *(const float4*)(src + 4);
  u16 tmp[8] = {f2bf(v0.x), f2bf(v0.y), f2bf(v0.z), f2bf(v0.w),
                f2bf(v1.x), f2bf(v1.y), f2bf(v1.z), f2bf(v1.w)};
  *(short8*)(xb + ((long)t * 64 + b) * 512 + d0) = *(short8*)tmp;
}

// ---------- fused LSTM: 256 WGs = 4 batch-groups x 64 u-tiles, persistent ----------
// h tile frag-ordered in LDS (conflict-free ds_read_b128); x A-frags in registers.
// Exchange: relaxed agent (LLC) stores/loads; per-WG flag padded to a full
// 128-B line (kills same-line contention); ordering = s_waitcnt vmcnt(0) +
// barrier (drains ALL waves' h stores) before the relaxed flag store.
__launch_bounds__(256, 1)
__global__ void lstm_fused(const float* __restrict__ kern, const float* __restrict__ rec,
                           const u16* __restrict__ xb, u32* __restrict__ hbuf,
                           u32* __restrict__ flags, float* __restrict__ out) {
  __shared__ u16   smH[32 * 64 * 8];     // 32,768 B, frag-ordered
  __shared__ float zbuf[4 * 16 * 17];    //  4,352 B

  const int bid = blockIdx.x;
  const int bg = bid >> 6;   // 0..3 batch group (64 WGs each)
  const int ut = bid & 63;   // 0..63 u tile
  const int tid = threadIdx.x;
  const int w = tid >> 6, lane = tid & 63;
  const int quad = lane >> 4, n15 = lane & 15;

  // ---- one-time: 48 register B-fragments (wf[0..31]=rec K=1024, wf[32..47]=kern K=512)
  short8 wf[48];
  const size_t gcol = (size_t)w * 1024 + (size_t)ut * 16 + (size_t)n15;
#pragma unroll
  for (int ks = 0; ks < 32; ++ks) {
    u16 tmp[8];
#pragma unroll
    for (int j = 0; j < 8; ++j)
      tmp[j] = f2bf(rec[(size_t)(ks * 32 + quad * 8 + j) * 4096 + gcol]);
    wf[ks] = *(short8*)tmp;
  }
#pragma unroll
  for (int ks = 0; ks < 16; ++ks) {
    u16 tmp[8];
#pragma unroll
    for (int j = 0; j < 8; ++j)
      tmp[j] = f2bf(kern[(size_t)(ks * 32 + quad * 8 + j) * 4096 + gcol]);
    wf[32 + ks] = *(short8*)tmp;
  }

  const int bl = tid >> 4;   // elementwise: batch-local 0..15
  const int ul = tid & 15;   // elementwise: u-local 0..15
  float c = 0.f;

  // ---- prologue: h0 = 0 in LDS; x0 A-frags -> registers ----
#pragma unroll
  for (int j = 0; j < 8; ++j)
    *(uint4*)(smH + (tid + j * 256) * 8) = (uint4){0u, 0u, 0u, 0u};

  short8 xf[16];
  {
    const u16* xr = xb + (size_t)(bg * 16 + n15) * 512 + quad * 8;
#pragma unroll
    for (int ks = 0; ks < 16; ++ks) xf[ks] = *(const short8*)(xr + ks * 32);
  }
  __syncthreads();

  for (int t = 0; t < 512; ++t) {
    // ---- z = h@R (LDS frags) + x@K (reg frags), dual acc chains ----
    f32x4 acc0 = {0.f, 0.f, 0.f, 0.f}, acc1 = {0.f, 0.f, 0.f, 0.f};
#pragma unroll
    for (int ks = 0; ks < 32; ks += 2) {
      short8 a0 = *(const short8*)(smH + (ks * 64 + lane) * 8);
      acc0 = __builtin_amdgcn_mfma_f32_16x16x32_bf16(a0, wf[ks], acc0, 0, 0, 0);
      short8 a1 = *(const short8*)(smH + ((ks + 1) * 64 + lane) * 8);
      acc1 = __builtin_amdgcn_mfma_f32_16x16x32_bf16(a1, wf[ks + 1], acc1, 0, 0, 0);
    }
#pragma unroll
    for (int ks = 0; ks < 16; ks += 2) {
      acc0 = __builtin_amdgcn_mfma_f32_16x16x32_bf16(xf[ks], wf[32 + ks], acc0, 0, 0, 0);
      acc1 = __builtin_amdgcn_mfma_f32_16x16x32_bf16(xf[ks + 1], wf[33 + ks], acc1, 0, 0, 0);
    }

    // ---- z exchange: zbuf[gate=w][batch=quad*4+r][u=n15] ----
    float* zp = zbuf + (w * 16 + quad * 4) * 17 + n15;
    zp[0]  = acc0[0] + acc1[0];
    zp[17] = acc0[1] + acc1[1];
    zp[34] = acc0[2] + acc1[2];
    zp[51] = acc0[3] + acc1[3];
    __syncthreads();                       // sync1: z ready; MFMA LDS reads done

    float zi = zbuf[(0 * 16 + bl) * 17 + ul];
    float zf = zbuf[(1 * 16 + bl) * 17 + ul];
    float zg = zbuf[(2 * 16 + bl) * 17 + ul];
    float zo = zbuf[(3 * 16 + bl) * 17 + ul];
    float ig = 1.f / (1.f + __expf(-zi));
    float fg = 1.f / (1.f + __expf(-zf));
    float gg = fast_tanh(zg);
    float og = 1.f / (1.f + __expf(-zo));
    c = fg * c + ig * gg;
    float h = og * fast_tanh(c);

    if (t == 511) {
      out[(size_t)(bg * 16 + bl) * 1024 + (size_t)ut * 16 + ul] = h;
      break;
    }

    const int pb = (t + 1) & 1;            // buffer receiving h_{t+1}

    // ---- publish straight from registers: pair-pack via shfl, even lanes store ----
    {
      u16 hu = f2bf(h);
      int other = __shfl_xor((int)(unsigned)hu, 1);
      if ((tid & 1) == 0) {
        u32 v = (u32)hu | ((u32)(unsigned)other << 16);
        __hip_atomic_store(&hbuf[(size_t)pb * 32768 + (size_t)(bg * 16 + bl) * 512
                                 + ut * 8 + (ul >> 1)],
                           v, __ATOMIC_RELAXED, __HIP_MEMORY_SCOPE_AGENT);
      }
    }
    // drain own stores, then barrier => ALL waves' h stores are LLC-acked
    __builtin_amdgcn_s_waitcnt(0x0F70);    // vmcnt(0) only
    __syncthreads();                       // sync2

    // ---- signal: relaxed store to OWN padded flag line (no wbl2, no RMW) ----
    if (tid == 0)
      __hip_atomic_store(&flags[(bg * 64 + ut) * 32], (u32)(t + 1),
                         __ATOMIC_RELAXED, __HIP_MEMORY_SCOPE_AGENT);

    // ---- waves 1-3: x_{t+1} A-frag prefetch now (covered by poll window) ----
    if (w != 0) {
      const u16* xr = xb + ((size_t)(t + 1) * 64 + bg * 16 + n15) * 512 + quad * 8;
#pragma unroll
      for (int ks = 0; ks < 16; ++ks) xf[ks] = *(const short8*)(xr + ks * 32);
    }

    // ---- wait: wave0 polls its group's 64 flag lines (relaxed, LLC) ----
    if (w == 0) {
      const u32 tgt = (u32)(t + 1);
      const u32* fp = &flags[(bg * 64 + lane) * 32];
      u32 v = __hip_atomic_load(fp, __ATOMIC_RELAXED, __HIP_MEMORY_SCOPE_AGENT);
      while (__ballot(v < tgt) != 0ull) {
        __builtin_amdgcn_s_sleep(1);
        v = __hip_atomic_load(fp, __ATOMIC_RELAXED, __HIP_MEMORY_SCOPE_AGENT);
      }
    }
    __syncthreads();                       // sync3: barrier passed for all waves

    // ---- wave0: its x prefetch (drains during reload below) ----
    if (w == 0) {
      const u16* xr = xb + ((size_t)(t + 1) * 64 + bg * 16 + n15) * 512 + quad * 8;
#pragma unroll
      for (int ks = 0; ks < 16; ++ks) xf[ks] = *(const short8*)(xr + ks * 32);
    }

    // ---- reload h_{t+1} -> smH (frag order). thread: ks = w*8+kk, lane slot ----
    {
      const u32* hs = hbuf + (size_t)pb * 32768 + (size_t)(bg * 16 + n15) * 512;
#pragma unroll
      for (int kk = 0; kk < 8; ++kk) {
        const int ks = w * 8 + kk;
        const u64* src = (const u64*)(hs + ks * 16 + quad * 4);
        u64 v0 = __hip_atomic_load(src,     __ATOMIC_RELAXED, __HIP_MEMORY_SCOPE_AGENT);
        u64 v1 = __hip_atomic_load(src + 1, __ATOMIC_RELAXED, __HIP_MEMORY_SCOPE_AGENT);
        u64 pair[2] = {v0, v1};
        *(uint4*)(smH + (ks * 64 + lane) * 8) = *(const uint4*)pair;
      }
    }
    __syncthreads();                       // sync4: smH ready for next MFMA
  }
}

extern "C" void kernel_launch(void* const* d_in, const int* in_sizes, int n_in,
                              void* d_out, int out_size, void* d_ws, size_t ws_size,
                              hipStream_t stream) {
  const float* x    = (const float*)d_in[0];
  const float* kern = (const float*)d_in[1];
  const float* rec  = (const float*)d_in[2];
  float* out = (float*)d_out;
  char* ws = (char*)d_ws;

  u16* xbp   = (u16*)(ws + WS_XB);
  u32* hbuf  = (u32*)(ws + WS_H);
  u32* flags = (u32*)(ws + WS_FLAG);

  // zero barrier flags (ws is re-poisoned to 0xAA before every launch)
  hipMemsetAsync(ws + WS_FLAG, 0, 32768, stream);

  conv_x<<<8192, 256, 0, stream>>>(x, xbp);

  lstm_fused<<<256, 256, 0, stream>>>(kern, rec, xbp, hbuf, flags, out);
}